// Round 6
// baseline (201.210 us; speedup 1.0000x reference)
//
#include <hip/hip_runtime.h>
#include <math.h>

// Problem constants (match reference)
constexpr int C   = 6;
constexpr int NR  = 2048;
constexpr int NC  = 2048;
constexpr int KS  = 10;
constexpr int PAD = 4;              // top/left circular halo

// R9: R2 structure (best: 67us) + non-temporal stores + bijective XCD swizzle.
// Evidence R2/R4/R7/R8: effective BW invariant at ~2.2-2.6 TB/s across waves x2
// and pipeline depth x3 -> saturated per-CU line-miss service (~64 pending
// lines x ~800 cyc RT = ~0.09 lines/cyc/CU; 3.7M total lines / (256 x 0.09)
// = 67us exactly). Concurrency can't help; round-trip CAN: FETCH_SIZE shows
// ~70% of the 96 MiB input re-misses to HBM each dispatch because 100 MB of
// output writes thrash the 256 MiB LLC. Fix (a): nt stores keep output out of
// LLC -> input stays resident -> read RT ~halves -> line rate ~2x. Fix (b):
// XCD-bijective block swizzle (768%8==0) makes the 9-row vertical halo
// re-reads hit the local per-XCD L2 instead of 8x-replicating.
constexpr int R    = 32;            // output rows per block
constexpr int NIT  = R + KS - 1;    // 41 streamed H-rows
constexpr int CPT  = 4;             // cols per thread
constexpr int BW   = 256 * CPT;     // 1024 cols per block
constexpr int NBX  = NC / BW;       // 2
constexpr int NBY  = NR / R;        // 64
constexpr int NBLK = NBX * NBY * C; // 768 = 3 blocks/CU exactly
constexpr int NXCD = 8;

typedef float f32x4 __attribute__((ext_vector_type(4)));

__device__ __constant__ float MTFf[C] = {0.38f, 0.34f, 0.34f, 0.26f, 0.22f, 0.23f};

__global__ __launch_bounds__(256, 3)   // VGPR cap ~168; ~95 live -> no spills
void s2_blur_nt(const float* __restrict__ x, float* __restrict__ out)
{
    // ---- bijective XCD swizzle: consecutive hardware blocks round-robin XCDs;
    // remap so XCD k owns L in [k*96,(k+1)*96) = y-contiguous bands (halo
    // neighbors share the local L2). 768 % 8 == 0 -> bijection is exact. ----
    const int bid = blockIdx.x;
    const int L   = (bid & (NXCD - 1)) * (NBLK / NXCD) + (bid >> 3);
    const int y   = L & (NBY - 1);          // strip index (fast within XCD band)
    const int ch2 = L >> 6;                 // 0..11
    const int xh  = ch2 & 1;                // column half
    const int c   = ch2 >> 1;               // channel

    const int t  = threadIdx.x;
    const int r0 = y * R;
    const int jt = xh * BW + t * CPT;       // first output col of this thread

    const float* xc = x   + (size_t)c * NR * NC;
    float*       oc = out + (size_t)c * NR * NC;

    // ---- per-thread fp32 weights (verified absmax 0.0039 << 0.0325) ----
    float w[KS];
    {
        float mtf    = MTFf[c];
        float sig    = 2.0f * sqrtf(-2.0f * logf(mtf) / (float)(M_PI * M_PI));
        float inv2s2 = 1.0f / (2.0f * sig * sig);
        float s = 0.0f;
        #pragma unroll
        for (int d = 0; d < KS; ++d) {
            float cd = -4.5f + (float)d;
            w[d] = expf(-cd * cd * inv2s2);
            s += w[d];
        }
        #pragma unroll
        for (int d = 0; d < KS; ++d) w[d] /= s;
    }

    // ---- per-lane wrapped float4-group offsets (loop-invariant; wrap is a
    // multiple of 4 floats so a 16B group never splits) ----
    const int off0 = (jt - PAD +  0 + NC) & (NC - 1);
    const int off1 = (jt - PAD +  4 + NC) & (NC - 1);
    const int off2 = (jt - PAD +  8 + NC) & (NC - 1);
    const int off3 = (jt - PAD + 12 + NC) & (NC - 1);

    // V-pass accumulator ring: slot m%10 holds strip-row m in flight
    float acc[KS][CPT];
    #pragma unroll
    for (int s = 0; s < KS; ++s)
        #pragma unroll
        for (int q = 0; q < CPT; ++q) acc[s][q] = 0.0f;

    // prime the pipeline: row k=0
    float4 f0, f1, f2, f3;
    {
        const float* rp = xc + (size_t)((r0 - PAD + NR) & (NR - 1)) * NC;
        f0 = *(const float4*)(rp + off0);
        f1 = *(const float4*)(rp + off1);
        f2 = *(const float4*)(rp + off2);
        f3 = *(const float4*)(rp + off3);
    }

    #pragma unroll
    for (int k = 0; k < NIT; ++k) {
        // prefetch row k+1 (loads in flight across ~85 FMAs + wave TLP)
        float4 g0, g1, g2, g3;
        if (k + 1 < NIT) {
            const float* rp = xc + (size_t)((r0 - PAD + k + 1) & (NR - 1)) * NC;
            g0 = *(const float4*)(rp + off0);
            g1 = *(const float4*)(rp + off1);
            g2 = *(const float4*)(rp + off2);
            g3 = *(const float4*)(rp + off3);
        }

        // ---- H-pass for row k: H[q] = sum_d w[d] * window[q+d] ----
        const float f[16] = {f0.x, f0.y, f0.z, f0.w,
                             f1.x, f1.y, f1.z, f1.w,
                             f2.x, f2.y, f2.z, f2.w,
                             f3.x, f3.y, f3.z, f3.w};
        float H[CPT];
        #pragma unroll
        for (int q = 0; q < CPT; ++q) {
            float a = 0.0f;
            #pragma unroll
            for (int d = 0; d < KS; ++d) a = fmaf(w[d], f[q + d], a);
            H[q] = a;
        }

        // ---- V-pass ring update: H row k feeds strip rows m = k-o, weight w[o] ----
        #pragma unroll
        for (int o = 0; o < KS; ++o) {
            const int m = k - o;
            if (m >= 0 && m < R) {
                const int s = m % KS;
                #pragma unroll
                for (int q = 0; q < CPT; ++q)
                    acc[s][q] = fmaf(w[o], H[q], acc[s][q]);
            }
        }

        // ---- emit finished strip row m = k-9 (non-temporal: keep out of LLC) ----
        if (k >= KS - 1) {
            const int m = k - (KS - 1);
            const int s = m % KS;
            float* orow = oc + (size_t)(r0 + m) * NC;   // wave-uniform base
            f32x4 v = {acc[s][0], acc[s][1], acc[s][2], acc[s][3]};
            __builtin_nontemporal_store(v, (f32x4*)(orow + jt));
            #pragma unroll
            for (int q = 0; q < CPT; ++q) acc[s][q] = 0.0f;
        }

        f0 = g0; f1 = g1; f2 = g2; f3 = g3;
    }
}

extern "C" void kernel_launch(void* const* d_in, const int* in_sizes, int n_in,
                              void* d_out, int out_size, void* d_ws, size_t ws_size,
                              hipStream_t stream) {
    const float* x = (const float*)d_in[0];
    float* out = (float*)d_out;
    dim3 grid(NBLK, 1, 1);   // flattened for XCD swizzle; 768 = 3 blocks/CU
    dim3 block(256);
    s2_blur_nt<<<grid, block, 0, stream>>>(x, out);
}